// Round 1
// baseline (399.463 us; speedup 1.0000x reference)
//
#include <hip/hip_runtime.h>
#include <hip/hip_bf16.h>

typedef _Float16 half8 __attribute__((ext_vector_type(8)));
typedef float floatx4 __attribute__((ext_vector_type(4)));

#define MFMA16H(a, b, c) __builtin_amdgcn_mfma_f32_16x16x32_f16((a), (b), (c), 0, 0, 0)

static constexpr int Bb = 8, Nn = 2048, Mm = 2048, Dd = 256;

__device__ inline half8 cvt8h(const float* __restrict__ p)
{
    float4 f0 = *reinterpret_cast<const float4*>(p);
    float4 f1 = *reinterpret_cast<const float4*>(p + 4);
    half8 r;
    r[0] = (_Float16)f0.x; r[1] = (_Float16)f0.y; r[2] = (_Float16)f0.z; r[3] = (_Float16)f0.w;
    r[4] = (_Float16)f1.x; r[5] = (_Float16)f1.y; r[6] = (_Float16)f1.z; r[7] = (_Float16)f1.w;
    return r;
}

__device__ inline void cvt8h_split(const float* __restrict__ p, half8& h, half8& l)
{
    float4 f0 = *reinterpret_cast<const float4*>(p);
    float4 f1 = *reinterpret_cast<const float4*>(p + 4);
    float f[8] = {f0.x, f0.y, f0.z, f0.w, f1.x, f1.y, f1.z, f1.w};
#pragma unroll
    for (int i = 0; i < 8; ++i) {
        _Float16 hh = (_Float16)f[i];
        h[i] = hh;
        l[i] = (_Float16)(f[i] - (float)hh);
    }
}

// ---------------------------------------------------------------------------
// prep: [0,1024)   Fi -> FiH fp16 + FiT fp16 transpose (XOR-swizzled LDS tile)
//       [1024,1056) W -> Wh/Wl fp16 hi/lo split
// ---------------------------------------------------------------------------
__global__ __launch_bounds__(256, 4)
void prep_kernel(const float* __restrict__ Fi, const float* __restrict__ W,
                 _Float16* __restrict__ FiH, _Float16* __restrict__ FiT,
                 _Float16* __restrict__ Wh, _Float16* __restrict__ Wl)
{
    const int bid = blockIdx.x;
    const int t = threadIdx.x;

    if (bid >= 1024) {                      // W split
        const size_t base = (size_t)(bid - 1024) * 2048 + t * 8;
        half8 h, l;
        cvt8h_split(W + base, h, l);
        *(half8*)(Wh + base) = h;
        *(half8*)(Wl + base) = l;
        return;
    }

    // logical tile[i][j] stored at [i][ (j&15) + 16*((j>>4)^(i>>4)) ]
    __shared__ __align__(16) unsigned short tile[64][64];
    const int b  = bid >> 7;
    const int mt = (bid >> 2) & 31;
    const int dt = bid & 3;
    {
        const int i = t >> 2, jc = (t & 3) * 16;
        const int pc = ((jc >> 4) ^ (i >> 4)) * 16;
        const float* src = Fi + ((size_t)b * Mm + mt * 64 + i) * Dd + dt * 64 + jc;
        union { half8 v; uint4 u; } p0, p1;
        p0.v = cvt8h(src);
        p1.v = cvt8h(src + 8);
        *(uint4*)&tile[i][pc]     = p0.u;
        *(uint4*)&tile[i][pc + 8] = p1.u;
        unsigned short* dh = reinterpret_cast<unsigned short*>(FiH)
            + ((size_t)b * Mm + mt * 64 + i) * Dd + dt * 64 + jc;
        *(uint4*)dh       = p0.u;
        *(uint4*)(dh + 8) = p1.u;
    }
    __syncthreads();
    {
        const int d = t >> 2, mc = (t & 3) * 16;
        unsigned short* dst = reinterpret_cast<unsigned short*>(FiT)
            + ((size_t)b * Dd + dt * 64 + d) * Mm + mt * 64 + mc;
        union { uint4 v[2]; unsigned short s[16]; } u;
#pragma unroll
        for (int s = 0; s < 16; ++s) {
            const int row = mc + s;
            u.s[s] = tile[row][((d >> 4) ^ (row >> 4)) * 16 + (d & 15)];
        }
        *(uint4*)dst       = u.v[0];
        *(uint4*)(dst + 8) = u.v[1];
    }
}

// ---------------------------------------------------------------------------
// qproj v2: barrier-free. W fragments read DIRECTLY from global (Wh/Wl are
// 256 KB total -> L2-resident on every XCD); no LDS, no __syncthreads.
// grid 1024 x 256 thr: block = 16 rows; wave w owns output cols [w*64, w*64+64).
// ---------------------------------------------------------------------------
__global__ __launch_bounds__(256, 4)
void qproj_kernel(const float* __restrict__ x, const _Float16* __restrict__ Wh,
                  const _Float16* __restrict__ Wl, const float* __restrict__ bias,
                  _Float16* __restrict__ q)
{
    const int tid = threadIdx.x;
    const int lane = tid & 63, w = tid >> 6;
    const int lo = lane & 15, hi = lane >> 4;
    const long r0 = (long)blockIdx.x * 16;

    floatx4 acc[4];
#pragma unroll
    for (int j = 0; j < 4; ++j) acc[j] = (floatx4)0.0f;

#pragma unroll 2
    for (int k0 = 0; k0 < 256; k0 += 32) {
        half8 ah, al;
        cvt8h_split(x + (size_t)(r0 + lo) * Dd + k0 + hi * 8, ah, al);
#pragma unroll
        for (int jj = 0; jj < 4; ++jj) {
            const int e = (w * 4 + jj) * 16 + lo;
            half8 bh = *reinterpret_cast<const half8*>(Wh + (size_t)e * Dd + k0 + hi * 8);
            half8 bl = *reinterpret_cast<const half8*>(Wl + (size_t)e * Dd + k0 + hi * 8);
            acc[jj] = MFMA16H(ah, bh, acc[jj]);
            acc[jj] = MFMA16H(ah, bl, acc[jj]);
            acc[jj] = MFMA16H(al, bh, acc[jj]);
        }
    }
#pragma unroll
    for (int jj = 0; jj < 4; ++jj) {
        const int e = (w * 4 + jj) * 16 + lo;
        const float bv = bias[e];
#pragma unroll
        for (int r = 0; r < 4; ++r)
            q[(size_t)(r0 + hi * 4 + r) * Dd + e] = (_Float16)(acc[jj][r] + bv);
    }
}

// ---------------------------------------------------------------------------
// flash v2: BARRIER-FREE. FiH/FiT fragments read directly from global:
// per-(b,kh) slice is 512 KB and all 16 sharing blocks sit on the same XCD
// (bid % 8 == b), so reads are L2-hits. No staging LDS, no __syncthreads --
// each wave free-runs; the co-resident waves hide L2 latency.
// sP (P roundtrip) and sO (epilogue transpose for coalesced o_part stores)
// are per-wave, needing only in-wave lgkmcnt ordering.
// grid 512 = 8b x 16nt x 4kh, 256 thr (4 waves x 32 rows).
// ---------------------------------------------------------------------------
__global__ __launch_bounds__(256, 2)
void flash_kernel(const _Float16* __restrict__ q, const _Float16* __restrict__ FiH,
                  const _Float16* __restrict__ FiT, _Float16* __restrict__ o_part,
                  float* __restrict__ m_part, float* __restrict__ l_part)
{
    __shared__ __align__(16) _Float16 sP[4][32 * 36];    // per-wave P, pitch 36
    __shared__ __align__(16) _Float16 sO[4][16][280];    // per-wave epilogue transpose

    const int bid = blockIdx.x;
    const int b  = bid & 7;
    const int u  = bid >> 3;
    const int nt = u & 15;
    const int kh = u >> 4;
    const int tid = threadIdx.x;
    const int lane = tid & 63, w = tid >> 6;
    const int lo = lane & 15, hi = lane >> 4;
    const int nbase = nt * 128 + w * 32;

    const _Float16* fH = FiH + (size_t)b * Mm * Dd;
    const _Float16* fT = FiT + (size_t)b * Dd * Mm;

    // Q fragments (A layout: A[m=lo][k=hi*8+j])
    half8 qf[2][8];
    const _Float16* qb = q + ((size_t)b * Nn + nbase + lo) * Dd + hi * 8;
#pragma unroll
    for (int rt = 0; rt < 2; ++rt)
#pragma unroll
        for (int kk = 0; kk < 8; ++kk)
            qf[rt][kk] = *reinterpret_cast<const half8*>(qb + rt * 16 * Dd + kk * 32);

    half8 ones;
#pragma unroll
    for (int i = 0; i < 8; ++i) ones[i] = (_Float16)1.0f;

    floatx4 o[2][16];
    floatx4 ol[2];
#pragma unroll
    for (int rt = 0; rt < 2; ++rt) {
#pragma unroll
        for (int t = 0; t < 16; ++t) o[rt][t] = (floatx4)0.0f;
        ol[rt] = (floatx4)0.0f;
    }
    float m_i[2][4];
#pragma unroll
    for (int rt = 0; rt < 2; ++rt)
#pragma unroll
        for (int r = 0; r < 4; ++r) m_i[rt][r] = -INFINITY;

    // per-lane global bases (linear layout; LDS XOR-unswizzle folds to identity)
    const _Float16* pH = fH + (size_t)(kh * 512 + lo) * Dd + hi * 8;  // +st*16*Dd, +kk*32
    const _Float16* pT = fT + (size_t)lo * Mm + kh * 512 + hi * 8;    // +t*16*Mm, +it*32

#pragma unroll 2
    for (int it = 0; it < 16; ++it) {
        // ---- QK^T: B fragments straight from L2
        floatx4 s[2][2];
#pragma unroll
        for (int rt = 0; rt < 2; ++rt)
#pragma unroll
            for (int st = 0; st < 2; ++st) s[rt][st] = (floatx4)0.0f;
#pragma unroll
        for (int st = 0; st < 2; ++st) {
            const _Float16* kb = pH + (size_t)(it * 32 + st * 16) * Dd;
#pragma unroll
            for (int kk = 0; kk < 8; ++kk) {
                half8 bv = *reinterpret_cast<const half8*>(kb + kk * 32);
                s[0][st] = MFMA16H(qf[0][kk], bv, s[0][st]);
                s[1][st] = MFMA16H(qf[1][kk], bv, s[1][st]);
            }
        }

        // ---- online softmax (unchanged)
        float mn[2][4];
        bool chg = false;
#pragma unroll
        for (int rt = 0; rt < 2; ++rt)
#pragma unroll
            for (int r = 0; r < 4; ++r) {
                float mc = fmaxf(s[rt][0][r], s[rt][1][r]);
                mc = fmaxf(mc, __shfl_xor(mc, 1));
                mc = fmaxf(mc, __shfl_xor(mc, 2));
                mc = fmaxf(mc, __shfl_xor(mc, 4));
                mc = fmaxf(mc, __shfl_xor(mc, 8));
                mn[rt][r] = fmaxf(m_i[rt][r], mc);
                chg = chg || (mn[rt][r] > m_i[rt][r]);
            }
        if (__any(chg)) {
#pragma unroll
            for (int rt = 0; rt < 2; ++rt) {
                float al4[4];
#pragma unroll
                for (int r = 0; r < 4; ++r) {
                    al4[r] = __expf(m_i[rt][r] - mn[rt][r]);
                    m_i[rt][r] = mn[rt][r];
                }
#pragma unroll
                for (int t = 0; t < 16; ++t) {
                    floatx4 ot = o[rt][t];
#pragma unroll
                    for (int r = 0; r < 4; ++r) ot[r] *= al4[r];
                    o[rt][t] = ot;
                }
#pragma unroll
                for (int r = 0; r < 4; ++r) ol[rt][r] *= al4[r];
            }
        }
#pragma unroll
        for (int rt = 0; rt < 2; ++rt)
#pragma unroll
            for (int r = 0; r < 4; ++r) {
                _Float16 p0 = (_Float16)__expf(s[rt][0][r] - m_i[rt][r]);
                _Float16 p1 = (_Float16)__expf(s[rt][1][r] - m_i[rt][r]);
                sP[w][(rt * 16 + hi * 4 + r) * 36 + lo]      = p0;
                sP[w][(rt * 16 + hi * 4 + r) * 36 + 16 + lo] = p1;
            }

        half8 pa0 = *reinterpret_cast<const half8*>(&sP[w][lo * 36 + hi * 8]);
        half8 pa1 = *reinterpret_cast<const half8*>(&sP[w][(16 + lo) * 36 + hi * 8]);

        // ---- PV: V fragments straight from L2
        const _Float16* vb = pT + it * 32;
#pragma unroll
        for (int t = 0; t < 16; ++t) {
            half8 bv = *reinterpret_cast<const half8*>(vb + (size_t)t * 16 * Mm);
            o[0][t] = MFMA16H(pa0, bv, o[0][t]);
            o[1][t] = MFMA16H(pa1, bv, o[1][t]);
        }
        ol[0] = MFMA16H(pa0, ones, ol[0]);
        ol[1] = MFMA16H(pa1, ones, ol[1]);
    }

    // ---- epilogue: LDS transpose -> coalesced 16B o_part stores;
    //      fp32 m/l partials (merge normalizes)
    const size_t gq0 = (size_t)kh * (Bb * Nn) + (size_t)b * Nn + nbase;
#pragma unroll
    for (int rt = 0; rt < 2; ++rt) {
#pragma unroll
        for (int t = 0; t < 16; ++t)
#pragma unroll
            for (int r = 0; r < 4; ++r)
                sO[w][hi * 4 + r][t * 16 + lo] = (_Float16)o[rt][t][r];
        if (lo == 0) {
#pragma unroll
            for (int r = 0; r < 4; ++r) {
                const size_t gq = gq0 + rt * 16 + hi * 4 + r;
                m_part[gq] = m_i[rt][r];
                l_part[gq] = ol[rt][r];
            }
        }
        const int row = lane >> 2, cq = lane & 3;     // 16 rows x 4 lanes
        _Float16* gp = o_part + (gq0 + rt * 16 + row) * Dd;
#pragma unroll
        for (int j = 0; j < 8; ++j) {
            half8 v = *reinterpret_cast<const half8*>(&sO[w][row][(j * 4 + cq) * 8]);
            *reinterpret_cast<half8*>(gp + (j * 4 + cq) * 8) = v;
        }
    }
}

// ---------------------------------------------------------------------------
// merge: combine 4 KV-split partials. grid 2048 x 256 thr, 8 rows/block.
// ---------------------------------------------------------------------------
__global__ __launch_bounds__(256, 8)
void merge_kernel(const _Float16* __restrict__ o_part, const float* __restrict__ m_part,
                  const float* __restrict__ l_part, float* __restrict__ out)
{
    const int col = threadIdx.x;
#pragma unroll
    for (int rr = 0; rr < 8; ++rr) {
        const int row = blockIdx.x * 8 + rr;
        float m[4], l[4];
#pragma unroll
        for (int k = 0; k < 4; ++k) {
            m[k] = m_part[(size_t)k * (Bb * Nn) + row];
            l[k] = l_part[(size_t)k * (Bb * Nn) + row];
        }
        float M = fmaxf(fmaxf(m[0], m[1]), fmaxf(m[2], m[3]));
        float denom = 0.f, acc = 0.f;
#pragma unroll
        for (int k = 0; k < 4; ++k) {
            const float wk = __expf(m[k] - M);
            denom += wk * l[k];
            acc += wk * (float)o_part[((size_t)k * (Bb * Nn) + row) * Dd + col];
        }
        out[(size_t)row * Dd + col] = acc / denom;
    }
}

// ---------------------------------------------------------------------------
extern "C" void kernel_launch(void* const* d_in, const int* in_sizes, int n_in,
                              void* d_out, int out_size, void* d_ws, size_t ws_size,
                              hipStream_t stream)
{
    const float* x    = (const float*)d_in[0];
    const float* Fi   = (const float*)d_in[1];
    const float* W    = (const float*)d_in[2];
    const float* bias = (const float*)d_in[3];
    float* out = (float*)d_out;

    _Float16* q_ws = (_Float16*)d_ws;                                // 8.4 MB
    _Float16* FiH  = q_ws + (size_t)Bb * Nn * Dd;                    // 8.4 MB
    _Float16* FiT  = FiH + (size_t)Bb * Mm * Dd;                     // 8.4 MB
    _Float16* Wh   = FiT + (size_t)Bb * Dd * Mm;                     // 128 KB
    _Float16* Wl   = Wh + (size_t)Dd * Dd;                           // 128 KB
    _Float16* o_part = Wl + (size_t)Dd * Dd;                         // 33.6 MB
    float* m_part  = (float*)(o_part + (size_t)4 * Bb * Nn * Dd);    // 256 KB
    float* l_part  = m_part + (size_t)4 * Bb * Nn;                   // 256 KB

    hipLaunchKernelGGL(prep_kernel, dim3(1056), dim3(256), 0, stream, Fi, W, FiH, FiT, Wh, Wl);
    hipLaunchKernelGGL(qproj_kernel, dim3(1024), dim3(256), 0, stream, x, Wh, Wl, bias, q_ws);
    hipLaunchKernelGGL(flash_kernel, dim3(512), dim3(256), 0, stream, q_ws, FiH, FiT,
                       o_part, m_part, l_part);
    hipLaunchKernelGGL(merge_kernel, dim3(2048), dim3(256), 0, stream, o_part, m_part, l_part, out);
}